// Round 1
// baseline (1420.427 us; speedup 1.0000x reference)
//
#include <hip/hip_runtime.h>
#include <hip/hip_bf16.h>

#define N_NODES 16384
#define E_EDGES 262144
#define F_INDIM 1024
#define H1DIM   256
#define NZDIM   64

typedef __attribute__((ext_vector_type(8))) short short8;
typedef __attribute__((ext_vector_type(4))) float f32x4;

// ---- bf16 helpers (round-to-nearest-even, manual to avoid API surprises) ----
__device__ inline short f2bf(float f) {
    unsigned int u = __builtin_bit_cast(unsigned int, f);
    unsigned int r = (u + 0x7fffu + ((u >> 16) & 1u)) >> 16;
    return (short)r;
}
__device__ inline float bf2f(short s) {
    unsigned int u = ((unsigned int)(unsigned short)s) << 16;
    return __builtin_bit_cast(float, u);
}

// ============================================================
// W1 split + transpose: W1[1024][256] f32 -> w1t_h/w1t_l [256][1024] bf16
// ============================================================
__global__ __launch_bounds__(256) void k_split_w1t(
    const float* __restrict__ W1, short* __restrict__ hi, short* __restrict__ lo) {
    int t = blockIdx.x * 256 + threadIdx.x;      // 0..262143
    int k = t >> 8, n = t & 255;
    float f = W1[t];
    short h = f2bf(f);
    hi[n * 1024 + k] = h;
    lo[n * 1024 + k] = f2bf(f - bf2f(h));
}

// ============================================================
// CSR build: histogram, scan, scatter
// ============================================================
__global__ __launch_bounds__(256) void k_hist(
    const int* __restrict__ dst, int* __restrict__ cnt) {
    int e = blockIdx.x * 256 + threadIdx.x;
    atomicAdd(&cnt[dst[e]], 1);
}

__global__ __launch_bounds__(1024) void k_scan(
    const int* __restrict__ cnt, int* __restrict__ row_start, int* __restrict__ cursor) {
    __shared__ int part[1024];
    int t = threadIdx.x;
    int base = t * 16;
    int local[16];
    int s = 0;
#pragma unroll
    for (int i = 0; i < 16; i++) { local[i] = s; s += cnt[base + i]; }
    part[t] = s;
    __syncthreads();
    for (int off = 1; off < 1024; off <<= 1) {
        int v = (t >= off) ? part[t - off] : 0;
        __syncthreads();
        part[t] += v;
        __syncthreads();
    }
    int prefix = (t == 0) ? 0 : part[t - 1];
#pragma unroll
    for (int i = 0; i < 16; i++) {
        int v = prefix + local[i];
        row_start[base + i] = v;
        cursor[base + i] = v;
    }
    if (t == 1023) row_start[N_NODES] = part[1023];
}

__global__ __launch_bounds__(256) void k_scatter(
    const int* __restrict__ dst, int* __restrict__ cursor, int* __restrict__ perm) {
    int e = blockIdx.x * 256 + threadIdx.x;
    int pos = atomicAdd(&cursor[dst[e]], 1);
    perm[pos] = e;
}

// ============================================================
// GEMM1: support1[16384][256] = x[16384][1024] @ W1[1024][256]
// split-bf16 MFMA (hi*hi + hi*lo + lo*hi), x converted in staging.
// Tile BM=128 BN=64 BK=32; 4 waves (2x2), each 64x32 (4x2 16x16 frags).
// ============================================================
#define G1_PAD 56   // padded K-stride in elements (112B rows: 16B-aligned, ~2-way banks)

__global__ __launch_bounds__(256) void k_gemm1(
    const float* __restrict__ x,
    const short* __restrict__ wh, const short* __restrict__ wl,  // [256][1024]
    float* __restrict__ out) {                                    // [16384][256]
    __shared__ short Ah[128 * G1_PAD], Al[128 * G1_PAD];
    __shared__ short Bh[64 * G1_PAD],  Bl[64 * G1_PAD];

    int t = threadIdx.x;
    int wid = t >> 6, l = t & 63;
    int wm = wid >> 1, wn = wid & 1;
    int lr = l & 15, lg = l >> 4;
    long rowbase = (long)blockIdx.x * 128;
    int  colbase = blockIdx.y * 64;

    f32x4 acc[4][2];
#pragma unroll
    for (int m = 0; m < 4; m++)
#pragma unroll
        for (int n = 0; n < 2; n++) acc[m][n] = (f32x4){0.f, 0.f, 0.f, 0.f};

    // staging assignment
    int arow = t >> 1;            // 0..127
    int acol = (t & 1) << 4;      // 0 or 16
    int brow = t >> 2;            // 0..63
    int bcol = (t & 3) << 3;      // 0,8,16,24
    const float* gA  = &x[(rowbase + arow) * 1024 + acol];
    const short* gBh = &wh[(size_t)(colbase + brow) * 1024 + bcol];
    const short* gBl = &wl[(size_t)(colbase + brow) * 1024 + bcol];

    for (int k0 = 0; k0 < 1024; k0 += 32) {
        // issue global loads early
        f32x4 v0 = *(const f32x4*)(gA + k0);
        f32x4 v1 = *(const f32x4*)(gA + k0 + 4);
        f32x4 v2 = *(const f32x4*)(gA + k0 + 8);
        f32x4 v3 = *(const f32x4*)(gA + k0 + 12);
        short8 vbh = *(const short8*)(gBh + k0);
        short8 vbl = *(const short8*)(gBl + k0);

        // split f32 -> bf16 hi/lo
        short8 h0, l0, h1, l1;
#pragma unroll
        for (int j = 0; j < 4; j++) {
            float f;
            f = v0[j]; h0[j] = f2bf(f);     l0[j] = f2bf(f - bf2f(h0[j]));
            f = v1[j]; h0[4 + j] = f2bf(f); l0[4 + j] = f2bf(f - bf2f(h0[4 + j]));
            f = v2[j]; h1[j] = f2bf(f);     l1[j] = f2bf(f - bf2f(h1[j]));
            f = v3[j]; h1[4 + j] = f2bf(f); l1[4 + j] = f2bf(f - bf2f(h1[4 + j]));
        }

        __syncthreads();  // previous iteration's LDS reads complete
        *(short8*)&Ah[arow * G1_PAD + acol]     = h0;
        *(short8*)&Ah[arow * G1_PAD + acol + 8] = h1;
        *(short8*)&Al[arow * G1_PAD + acol]     = l0;
        *(short8*)&Al[arow * G1_PAD + acol + 8] = l1;
        *(short8*)&Bh[brow * G1_PAD + bcol]     = vbh;
        *(short8*)&Bl[brow * G1_PAD + bcol]     = vbl;
        __syncthreads();

        short8 afh[4], afl[4], bfh[2], bfl[2];
#pragma unroll
        for (int m = 0; m < 4; m++) {
            int r = (wm * 64 + m * 16 + lr) * G1_PAD + lg * 8;
            afh[m] = *(const short8*)&Ah[r];
            afl[m] = *(const short8*)&Al[r];
        }
#pragma unroll
        for (int n = 0; n < 2; n++) {
            int r = (wn * 32 + n * 16 + lr) * G1_PAD + lg * 8;
            bfh[n] = *(const short8*)&Bh[r];
            bfl[n] = *(const short8*)&Bl[r];
        }
#pragma unroll
        for (int m = 0; m < 4; m++)
#pragma unroll
            for (int n = 0; n < 2; n++) {
                acc[m][n] = __builtin_amdgcn_mfma_f32_16x16x32_bf16(afh[m], bfh[n], acc[m][n], 0, 0, 0);
                acc[m][n] = __builtin_amdgcn_mfma_f32_16x16x32_bf16(afh[m], bfl[n], acc[m][n], 0, 0, 0);
                acc[m][n] = __builtin_amdgcn_mfma_f32_16x16x32_bf16(afl[m], bfh[n], acc[m][n], 0, 0, 0);
            }
    }

    // epilogue: C layout col=l&15, row=(l>>4)*4+j
#pragma unroll
    for (int m = 0; m < 4; m++)
#pragma unroll
        for (int n = 0; n < 2; n++)
#pragma unroll
            for (int j = 0; j < 4; j++) {
                long row = rowbase + wm * 64 + m * 16 + lg * 4 + j;
                int  col = colbase + wn * 32 + n * 16 + lr;
                out[row * 256 + col] = acc[m][n][j];
            }
}

// ============================================================
// SPMM1: hidden1[d][0:256] = relu( sum_{e: dst=d} w_e * support1[src_e] )
// one wave per dst row; lane-parallel edge metadata + shfl broadcast
// ============================================================
__global__ __launch_bounds__(256) void k_spmm1(
    const float* __restrict__ sup, const int* __restrict__ row_start,
    const int* __restrict__ perm, const int* __restrict__ src,
    const float* __restrict__ ew, float* __restrict__ out) {
    int wid = threadIdx.x >> 6, l = threadIdx.x & 63;
    int d = blockIdx.x * 4 + wid;
    int s0 = row_start[d], s1 = row_start[d + 1];
    int nedge = s1 - s0;
    f32x4 acc = (f32x4){0.f, 0.f, 0.f, 0.f};
    for (int base = 0; base < nedge; base += 64) {
        int cnt = min(64, nedge - base);
        int e = (l < cnt) ? perm[s0 + base + l] : 0;
        int sv = (l < cnt) ? src[e] : 0;
        float wv = (l < cnt) ? ew[e] : 0.f;
        for (int i = 0; i < cnt; i++) {
            int s = __shfl(sv, i);
            float w = __shfl(wv, i);
            f32x4 v = *(const f32x4*)&sup[(size_t)s * 256 + l * 4];
            acc = acc + v * w;
        }
    }
    f32x4 r;
#pragma unroll
    for (int j = 0; j < 4; j++) r[j] = fmaxf(acc[j], 0.f);
    *(f32x4*)&out[(size_t)d * 256 + l * 4] = r;
}

// ============================================================
// GEMM2: support2[16384][64] = hidden1[16384][256] @ W2[256][64]  (f32 vector)
// ============================================================
__global__ __launch_bounds__(256) void k_gemm2(
    const float* __restrict__ hidden, const float* __restrict__ W2,
    float* __restrict__ out) {
    __shared__ float w2s[256 * 64];
    int t = threadIdx.x;
#pragma unroll
    for (int i = 0; i < 16; i++)
        ((f32x4*)w2s)[i * 256 + t] = ((const f32x4*)W2)[i * 256 + t];
    __syncthreads();
    int c = t & 63, rg = t >> 6;
    long rowbase = (long)blockIdx.x * 16;
    for (int rr = 0; rr < 4; rr++) {
        long row = rowbase + rr * 4 + rg;
        const float* hrow = &hidden[row * 256];
        float acc = 0.f;
#pragma unroll 8
        for (int k = 0; k < 256; k++) acc += hrow[k] * w2s[k * 64 + c];
        out[row * 64 + c] = acc;
    }
}

// ============================================================
// SPMM2 + relu + bf16 split: z = relu(spmm(support2)); write z f32 (d_out tail)
// and z_hi/z_lo bf16 for the zz^T MFMA.
// ============================================================
__global__ __launch_bounds__(256) void k_spmm2(
    const float* __restrict__ sup, const int* __restrict__ row_start,
    const int* __restrict__ perm, const int* __restrict__ src,
    const float* __restrict__ ew, float* __restrict__ zout,
    short* __restrict__ zh, short* __restrict__ zl) {
    int wid = threadIdx.x >> 6, l = threadIdx.x & 63;
    int d = blockIdx.x * 4 + wid;
    int s0 = row_start[d], s1 = row_start[d + 1];
    int nedge = s1 - s0;
    float acc = 0.f;
    for (int base = 0; base < nedge; base += 64) {
        int cnt = min(64, nedge - base);
        int e = (l < cnt) ? perm[s0 + base + l] : 0;
        int sv = (l < cnt) ? src[e] : 0;
        float wv = (l < cnt) ? ew[e] : 0.f;
        for (int i = 0; i < cnt; i++) {
            int s = __shfl(sv, i);
            float w = __shfl(wv, i);
            acc += w * sup[(size_t)s * 64 + l];
        }
    }
    float z = fmaxf(acc, 0.f);
    size_t idx = (size_t)d * 64 + l;
    zout[idx] = z;
    short h = f2bf(z);
    zh[idx] = h;
    zl[idx] = f2bf(z - bf2f(h));
}

// ============================================================
// ZZT: a_bar = z @ z^T, split-bf16 MFMA, K=64, frags direct from global.
// grid (128,128); 4 waves (2x2) each compute 64x64.
// ============================================================
__global__ __launch_bounds__(256) void k_zzt(
    const short* __restrict__ zh, const short* __restrict__ zl,
    float* __restrict__ out) {
    int t = threadIdx.x;
    int wid = t >> 6, l = t & 63;
    int wm = wid >> 1, wn = wid & 1;
    long rb = (long)blockIdx.y * 128 + wm * 64;
    long cb = (long)blockIdx.x * 128 + wn * 64;
    int lr = l & 15, lg = l >> 4;

    // B frags: B[k][c] = z[cb+c][k]; lane 16g+c holds k = 32*ks + 8g + j
    short8 bh[4][2], bl[4][2];
#pragma unroll
    for (int n = 0; n < 4; n++)
#pragma unroll
        for (int ks = 0; ks < 2; ks++) {
            long o = (cb + n * 16 + lr) * 64 + ks * 32 + lg * 8;
            bh[n][ks] = *(const short8*)&zh[o];
            bl[n][ks] = *(const short8*)&zl[o];
        }

    f32x4 acc[4][4];
#pragma unroll
    for (int m = 0; m < 4; m++)
#pragma unroll
        for (int n = 0; n < 4; n++) acc[m][n] = (f32x4){0.f, 0.f, 0.f, 0.f};

#pragma unroll
    for (int m = 0; m < 4; m++) {
        short8 ah[2], al[2];
#pragma unroll
        for (int ks = 0; ks < 2; ks++) {
            long o = (rb + m * 16 + lr) * 64 + ks * 32 + lg * 8;
            ah[ks] = *(const short8*)&zh[o];
            al[ks] = *(const short8*)&zl[o];
        }
#pragma unroll
        for (int n = 0; n < 4; n++)
#pragma unroll
            for (int ks = 0; ks < 2; ks++) {
                acc[m][n] = __builtin_amdgcn_mfma_f32_16x16x32_bf16(ah[ks], bh[n][ks], acc[m][n], 0, 0, 0);
                acc[m][n] = __builtin_amdgcn_mfma_f32_16x16x32_bf16(ah[ks], bl[n][ks], acc[m][n], 0, 0, 0);
                acc[m][n] = __builtin_amdgcn_mfma_f32_16x16x32_bf16(al[ks], bh[n][ks], acc[m][n], 0, 0, 0);
            }
    }

#pragma unroll
    for (int m = 0; m < 4; m++)
#pragma unroll
        for (int n = 0; n < 4; n++)
#pragma unroll
            for (int j = 0; j < 4; j++) {
                long row = rb + m * 16 + lg * 4 + j;
                long col = cb + n * 16 + lr;
                out[row * 16384 + col] = acc[m][n][j];
            }
}

// ============================================================
extern "C" void kernel_launch(void* const* d_in, const int* in_sizes, int n_in,
                              void* d_out, int out_size, void* d_ws, size_t ws_size,
                              hipStream_t stream) {
    (void)in_sizes; (void)n_in; (void)out_size; (void)ws_size;
    const float* x  = (const float*)d_in[0];
    const float* W1 = (const float*)d_in[1];
    const float* W2 = (const float*)d_in[2];
    const float* ew = (const float*)d_in[3];
    const int*   ei = (const int*)d_in[4];
    const int* esrc = ei;             // edge_index[0]
    const int* edst = ei + E_EDGES;   // edge_index[1]

    float* abar = (float*)d_out;
    float* zout = abar + (size_t)N_NODES * N_NODES;

    char* ws = (char*)d_ws;
    size_t off = 0;
    auto alloc = [&](size_t bytes) -> void* {
        void* p = ws + off;
        off += (bytes + 255) & ~(size_t)255;
        return p;
    };
    short* wh   = (short*)alloc((size_t)H1DIM * F_INDIM * 2);   // 512KB
    short* wl   = (short*)alloc((size_t)H1DIM * F_INDIM * 2);
    float* sup1 = (float*)alloc((size_t)N_NODES * H1DIM * 4);   // 16.8MB
    float* hid1 = (float*)alloc((size_t)N_NODES * H1DIM * 4);
    float* sup2 = (float*)alloc((size_t)N_NODES * NZDIM * 4);   // 4.2MB
    short* zh   = (short*)alloc((size_t)N_NODES * NZDIM * 2);
    short* zl   = (short*)alloc((size_t)N_NODES * NZDIM * 2);
    int*   cnt  = (int*)alloc((size_t)N_NODES * 4);
    int*   rows = (int*)alloc((size_t)(N_NODES + 1) * 4);
    int*   curs = (int*)alloc((size_t)N_NODES * 4);
    int*   perm = (int*)alloc((size_t)E_EDGES * 4);

    hipMemsetAsync(cnt, 0, (size_t)N_NODES * 4, stream);
    k_split_w1t<<<1024, 256, 0, stream>>>(W1, wh, wl);
    k_hist<<<E_EDGES / 256, 256, 0, stream>>>(edst, cnt);
    k_scan<<<1, 1024, 0, stream>>>(cnt, rows, curs);
    k_scatter<<<E_EDGES / 256, 256, 0, stream>>>(edst, curs, perm);
    k_gemm1<<<dim3(128, 4), 256, 0, stream>>>(x, wh, wl, sup1);
    k_spmm1<<<N_NODES / 4, 256, 0, stream>>>(sup1, rows, perm, esrc, ew, hid1);
    k_gemm2<<<N_NODES / 16, 256, 0, stream>>>(hid1, W2, sup2);
    k_spmm2<<<N_NODES / 4, 256, 0, stream>>>(sup2, rows, perm, esrc, ew, zout, zh, zl);
    k_zzt<<<dim3(128, 128), 256, 0, stream>>>(zh, zl, abar);
}